// Round 1
// baseline (669.375 us; speedup 1.0000x reference)
//
#include <hip/hip_runtime.h>

// SignalingModel: X_{t+1} = mml(W @ X_t + X_bias), 60 steps, W is 0.24% sparse.
// Strategy: extract sparsity per-launch (deterministic), then 1 block per sample
// with the 2048-node state in LDS (ping-pong), 60 steps inside the block.

#define NN 2048       // nodes
#define KSLOT 32      // max edges per target node (Poisson(5); P(>=32) ~ 1e-14)
#define STEPS 60
#define LEAKV 0.01f

// One wave (64 threads) per matrix row: compact nonzeros of row n into
// slot-major ELL: well[slot*NN + n], cell[slot*NN + n]. Coalesced both sides.
__global__ __launch_bounds__(64) void build_ell(const float* __restrict__ W,
                                                float* __restrict__ well,
                                                unsigned short* __restrict__ cell,
                                                int* __restrict__ cnt) {
  const int n = blockIdx.x;
  const int lane = threadIdx.x;
  int base = 0;
  for (int c0 = 0; c0 < NN; c0 += 64) {
    float w = W[n * NN + c0 + lane];
    unsigned long long m = __ballot(w != 0.0f);
    if (w != 0.0f) {
      int slot = base + __popcll(m & ((1ull << lane) - 1ull));
      if (slot < KSLOT) {
        well[slot * NN + n] = w;
        cell[slot * NN + n] = (unsigned short)(c0 + lane);
      }
    }
    base += __popcll(m);
  }
  if (lane == 0) cnt[n] = base < KSLOT ? base : KSLOT;
}

// One block per sample. State vector (2048 f32) ping-pongs in LDS.
// Thread t owns nodes {t, t+256, ..., t+1792} -> coalesced global I/O.
__global__ __launch_bounds__(256) void sim(const float* __restrict__ Xfull,
                                           const float* __restrict__ bias,
                                           const float* __restrict__ well,
                                           const unsigned short* __restrict__ cell,
                                           const int* __restrict__ cnt,
                                           float* __restrict__ out) {
  __shared__ float X2[2][NN];
  const int t = (int)threadIdx.x;
  const int s = (int)blockIdx.x;

  float xb[8];
  int c[8];
#pragma unroll
  for (int j = 0; j < 8; ++j) {
    const int n = j * 256 + t;
    xb[j] = Xfull[s * NN + n] + bias[n];  // X_bias[n][s] = X_full[s][n] + bias[n]
    c[j] = cnt[n];
    X2[0][n] = 0.0f;                      // X0 = 0
  }
  __syncthreads();

  int cur = 0;
  for (int it = 0; it < STEPS; ++it) {
#pragma unroll
    for (int j = 0; j < 8; ++j) {
      const int n = j * 256 + t;
      float acc = xb[j];
      const int cj = c[j];
      for (int k = 0; k < cj; ++k) {
        const int col = (int)cell[k * NN + n];   // coalesced (n contiguous over t)
        const float w = well[k * NN + n];
        acc += w * X2[cur][col];                 // random LDS gather, ~2-way banks
      }
      // mml: leak*x (x<0) | x (0<=x<0.5) | 1 - 0.25/x (x>=0.5)
      float y;
      if (acc < 0.0f)       y = LEAKV * acc;
      else if (acc < 0.5f)  y = acc;
      else                  y = 1.0f - 0.25f / acc;
      X2[cur ^ 1][n] = y;
    }
    __syncthreads();   // ping-pong: one barrier per step is sufficient
    cur ^= 1;
  }

#pragma unroll
  for (int j = 0; j < 8; ++j) {
    const int n = j * 256 + t;
    out[s * NN + n] = X2[cur][n];   // out is (B, N) row-major -> coalesced
  }
}

extern "C" void kernel_launch(void* const* d_in, const int* in_sizes, int n_in,
                              void* d_out, int out_size, void* d_ws, size_t ws_size,
                              hipStream_t stream) {
  const float* Xfull = (const float*)d_in[0];   // (B, N) f32
  const float* W     = (const float*)d_in[1];   // (N, N) f32, sparse content
  const float* bias  = (const float*)d_in[2];   // (N, 1) f32
  float* out = (float*)d_out;

  // workspace layout: well (KSLOT*NN f32 = 256 KB) | cell (KSLOT*NN u16 = 128 KB) | cnt (NN i32 = 8 KB)
  char* ws = (char*)d_ws;
  float* well = (float*)ws;
  unsigned short* cell = (unsigned short*)(ws + (size_t)KSLOT * NN * 4);
  int* cnt = (int*)(ws + (size_t)KSLOT * NN * 4 + (size_t)KSLOT * NN * 2);

  const int B = in_sizes[0] / NN;   // 512

  build_ell<<<NN, 64, 0, stream>>>(W, well, cell, cnt);
  sim<<<B, 256, 0, stream>>>(Xfull, bias, well, cell, cnt, out);
}